// Round 8
// baseline (223.862 us; speedup 1.0000x reference)
//
#include <hip/hip_runtime.h>

// GINE 2-layer GNN: N=50000 nodes, E=800000 edges, d=128.
// Round 20: delete bucket_csr. Buckets shrink to 32 nodes (= GR, NB=1563 so
// the gine grid keeps its verified 6.1 blocks/CU), scatter produces only
// bucket-grouped stage + B[], and each gine block counting-sorts its own
// ~512-edge bucket in LDS (raw edges staged into the As area, sorted into
// buf) before the node-parallel gather reads p-words from LDS. stage is now
// written once / read twice (was written twice / read three times), and the
// off[] array + one full-grid kernel disappear. The x->bf16 cast rides in
// scatter_cast (round-19's proven overlap trick, now under scatter latency).
// Scatter's in-kernel scan handles NB=1563>1024 via 2 buckets/thread
// (pair scan). gine gather/MFMA structure otherwise unchanged: GR=32,
// (256,4), pk-f32 math. bf16 feature path, f32 accumulation.

typedef unsigned long long u64;
typedef unsigned int u32;
typedef unsigned short ushort;
typedef __attribute__((ext_vector_type(8))) short short8;
typedef __attribute__((ext_vector_type(4))) float f32x4;
typedef __attribute__((ext_vector_type(2))) float f32x2;
typedef __attribute__((ext_vector_type(4))) u32 u32x4;   // native vec for NT ops

constexpr int NN = 50000;
constexpr int NE = 800000;
constexpr int D  = 128;
constexpr int BSH = 5;                    // 32 nodes per bucket
constexpr int NB  = (NN + 31) >> BSH;     // 1563 buckets
constexpr int NC  = 128;                  // edge chunks
constexpr int CHUNK = NE / NC;            // 6250
constexpr int BCAP = 1024;                // max edges/bucket (mean 512, +22s)
constexpr int GR = 32;                    // rows per gine block == bucket
constexpr int NU4 = NN * D / 8;           // 800000 uint4s to cast

__device__ __forceinline__ ushort f2bf(float f) {
    u32 u = __float_as_uint(f);
    return (ushort)((u + 0x7FFFu + ((u >> 16) & 1u)) >> 16);
}
__device__ __forceinline__ float bfl(u32 u) {            // low bf16 -> f32
    return __uint_as_float(u << 16);
}
__device__ __forceinline__ float bfh(u32 u) {            // high bf16 -> f32
    return __uint_as_float(u & 0xFFFF0000u);
}
__device__ __forceinline__ f32x2 unpk(u32 u) {           // packed bf16 -> 2xf32
    f32x2 r; r.x = bfl(u); r.y = bfh(u); return r;
}
__device__ __forceinline__ u64 pack_edge(int src, int d5, float w) {
    return ((u64)__float_as_uint(w) << 32) | (u32)(src | (d5 << 17));
}

// ---- hist_w: dst histogram (LDS, 32-node buckets) + transpose+cast W ----

__global__ __launch_bounds__(256) void hist_w(
    const float* __restrict__ W1, const float* __restrict__ W2,
    ushort* __restrict__ Wt1, ushort* __restrict__ Wt2,
    const int* __restrict__ dst, int* __restrict__ G)
{
    int blk = blockIdx.x;
    if (blk < NC) {
        __shared__ int hh[NB];
        int t = threadIdx.x, c = blk;
        for (int i = t; i < NB; i += 256) hh[i] = 0;
        __syncthreads();
        int e0 = c * CHUNK;
        for (int i = t; i < CHUNK; i += 256)
            atomicAdd(&hh[dst[e0 + i] >> BSH], 1);
        __syncthreads();
        for (int i = t; i < NB; i += 256) G[c * NB + i] = hh[i];
    } else {
        int b = blk - NC;                   // 0..7
        const float* W  = (b >= 4) ? W2 : W1;
        ushort*      Wt = (b >= 4) ? Wt2 : Wt1;
        int k0 = (b & 3) * 32;
        for (int i = threadIdx.x; i < 32 * D; i += 256) {
            int n = i >> 5, r = i & 31;
            Wt[n * D + k0 + r] = f2bf(W[(k0 + r) * D + n]);
        }
    }
}

// ---- scatter_cast: bucket-grouped scatter (pair scan, NB>1024) + x cast --

__global__ __launch_bounds__(1024) void scatter_cast(
    const int*   __restrict__ src,
    const int*   __restrict__ dst,
    const float* __restrict__ ew,
    const int*   __restrict__ G,
    int*         __restrict__ B,
    u64*         __restrict__ stage,
    const float* __restrict__ x,
    ushort*      __restrict__ xb)
{
    __shared__ int base_s[NB];          // 6.3 KB
    __shared__ int cnt_s[NB];           // 6.3 KB
    __shared__ int tsum[1024];          // 4 KB
    const int t = threadIdx.x, c = blockIdx.x;
    const int b0 = 2 * t, b1 = 2 * t + 1;

    // phase A: totals S and column prefixes P for my two buckets
    int S0 = 0, P0 = 0, S1 = 0, P1 = 0;
    if (b0 < NB) {
        #pragma unroll 8
        for (int cc = 0; cc < NC; ++cc) {
            int g = G[cc * NB + b0];
            S0 += g;
            if (cc < c) P0 += g;
        }
    }
    if (b1 < NB) {
        #pragma unroll 8
        for (int cc = 0; cc < NC; ++cc) {
            int g = G[cc * NB + b1];
            S1 += g;
            if (cc < c) P1 += g;
        }
    }
    tsum[t] = S0 + S1;

    // cast a slab of x -> bf16 (independent streaming, overlaps scan waits)
    #pragma unroll
    for (int j = 0; j < 7; ++j) {
        int i = (c + j * NC) * 1024 + t;
        if (i < NU4) {
            int base = i * 8;
            float4 a = *(const float4*)(x + base);
            float4 d = *(const float4*)(x + base + 4);
            uint4 o;
            o.x = (u32)f2bf(a.x) | ((u32)f2bf(a.y) << 16);
            o.y = (u32)f2bf(a.z) | ((u32)f2bf(a.w) << 16);
            o.z = (u32)f2bf(d.x) | ((u32)f2bf(d.y) << 16);
            o.w = (u32)f2bf(d.z) | ((u32)f2bf(d.w) << 16);
            *(uint4*)(xb + base) = o;
        }
    }
    __syncthreads();

    // phase B: inclusive scan of the 1024 pair totals
    for (int d = 1; d < 1024; d <<= 1) {
        int v = (t >= d) ? tsum[t - d] : 0;
        __syncthreads();
        tsum[t] += v;
        __syncthreads();
    }
    int pairbase = tsum[t] - (S0 + S1);     // exclusive prefix of my pair

    if (b0 < NB) {
        base_s[b0] = pairbase + P0;
        cnt_s[b0] = 0;
    }
    if (b1 < NB) {
        base_s[b1] = pairbase + S0 + P1;
        cnt_s[b1] = 0;
    }
    if (c == 0) {                            // publish B for gine_layer
        if (b0 < NB) B[b0] = pairbase;
        if (b1 < NB) B[b1] = pairbase + S0;
        if (t == 0)  B[NB] = NE;
    }
    __syncthreads();

    // phase C: scatter my chunk (16 waves -> latency hidden)
    int e0 = c * CHUNK;
    for (int i = t; i < CHUNK; i += 1024) {
        int e  = e0 + i;
        int d  = dst[e];
        int bk = d >> BSH;
        int r  = atomicAdd(&cnt_s[bk], 1);
        stage[base_s[bk] + r] = pack_edge(src[e], d & 31, ew[e]);
    }
}

// ---- fused layer: LDS counting sort + aggregate + self + MFMA gemm ----
// out = (relu?)((h + sum_{e->n} relu(h[src_e] + w_e*We + be)) @ W + bias)

__global__ __launch_bounds__(256, 4) void gine_layer(
    const ushort* __restrict__ hb,     // input features bf16 [NN][D]
    const int*    __restrict__ B,      // bucket starts in stage
    const u64*    __restrict__ epk,    // bucket-grouped packed edges
    const float*  __restrict__ We,
    const float*  __restrict__ be,
    const ushort* __restrict__ Wtb,    // transposed weight bf16 [D][D]
    const float*  __restrict__ bias,
    float*        __restrict__ outf,   // layer 2 (or null)
    ushort*       __restrict__ outb,   // layer 1 (or null)
    int relu)
{
    __shared__ u64 As64[GR * 140 / 4]; // 8.96 KB: raw edges, then bf16 As
    __shared__ u64 buf[BCAP];          // 8 KB node-sorted edges
    __shared__ int cnt[32];
    __shared__ int noff[32];
    __shared__ int cur[32];
    ushort* As = (ushort*)As64;

    const int t    = threadIdx.x;
    const int b    = blockIdx.x;
    const int row0 = b << BSH;

    // ---- phase 0: load bucket edges (coalesced) + counting sort in LDS ----
    int e0 = B[b];
    int n  = B[b + 1] - e0;
    if (n > BCAP) n = BCAP;
    if (t < 32) { cnt[t] = 0; cur[t] = 0; }
    __syncthreads();
    for (int i = t; i < n; i += 256) {
        u64 p = epk[e0 + i];
        As64[i] = p;                               // raw staging
        atomicAdd(&cnt[(int)((p >> 17) & 31)], 1);
    }
    __syncthreads();
    if (t == 0) {
        int run = 0;
        #pragma unroll
        for (int j = 0; j < 32; ++j) { noff[j] = run; run += cnt[j]; }
    }
    __syncthreads();
    for (int i = t; i < n; i += 256) {
        u64 p = As64[i];
        int d5 = (int)((p >> 17) & 31);
        int r = atomicAdd(&cur[d5], 1);
        buf[noff[d5] + r] = p;
    }
    __syncthreads();

    // ---- phase 1: aggregate edges + self term -> As (bf16) ----
    // 16 lanes per node, 8 features per lane (4x f32x2), 8-deep hv batch;
    // p-words now come from LDS (low latency, broadcast across the group).
    const int g  = t >> 4;             // node group 0..15
    const int d8 = (t & 15) << 3;

    f32x2 wv[4], bv[4];
    #pragma unroll
    for (int j = 0; j < 4; ++j) {
        wv[j] = *(const f32x2*)(We + d8 + 2 * j);
        bv[j] = *(const f32x2*)(be + d8 + 2 * j);
    }
    const f32x2 zero2 = {0.f, 0.f};

    for (int nrep = 0; nrep < GR / 16; ++nrep) {
        int ln = nrep * 16 + g;        // local row 0..GR-1
        int nd = row0 + ln;
        f32x2 a[4] = {zero2, zero2, zero2, zero2};
        if (nd < NN) {
            u32x4 sv = *(const u32x4*)(hb + (size_t)nd * D + d8);
            int s = noff[ln], deg = cnt[ln];
            for (int e = 0; e < deg; e += 8) {
                int m = deg - e; if (m > 8) m = 8;
                u64 p[8];
                #pragma unroll
                for (int k = 0; k < 8; ++k) p[k] = (k < m) ? buf[s + e + k] : 0;
                u32x4 hv[8];
                #pragma unroll
                for (int k = 0; k < 8; ++k)
                    hv[k] = *(const u32x4*)(hb + (size_t)(p[k] & 0x1FFFF) * D + d8);
                #pragma unroll
                for (int k = 0; k < 8; ++k) {
                    if (k < m) {
                        float w = __uint_as_float((u32)(p[k] >> 32));
                        f32x2 w2 = {w, w};
                        a[0] += __builtin_elementwise_max(zero2,
                                  unpk(hv[k].x) + __builtin_elementwise_fma(w2, wv[0], bv[0]));
                        a[1] += __builtin_elementwise_max(zero2,
                                  unpk(hv[k].y) + __builtin_elementwise_fma(w2, wv[1], bv[1]));
                        a[2] += __builtin_elementwise_max(zero2,
                                  unpk(hv[k].z) + __builtin_elementwise_fma(w2, wv[2], bv[2]));
                        a[3] += __builtin_elementwise_max(zero2,
                                  unpk(hv[k].w) + __builtin_elementwise_fma(w2, wv[3], bv[3]));
                    }
                }
            }
            // self term (h_n), f32 add before the single bf16 rounding
            a[0] += unpk(sv.x);
            a[1] += unpk(sv.y);
            a[2] += unpk(sv.z);
            a[3] += unpk(sv.w);
        }
        uint2 lo, hi;
        lo.x = (u32)f2bf(a[0].x) | ((u32)f2bf(a[0].y) << 16);
        lo.y = (u32)f2bf(a[1].x) | ((u32)f2bf(a[1].y) << 16);
        hi.x = (u32)f2bf(a[2].x) | ((u32)f2bf(a[2].y) << 16);
        hi.y = (u32)f2bf(a[3].x) | ((u32)f2bf(a[3].y) << 16);
        *(uint2*)&As[ln * 140 + d8]     = lo;
        *(uint2*)&As[ln * 140 + d8 + 4] = hi;
    }
    __syncthreads();

    // ---- phase 2: MFMA gemm, 32x128 output; B-fragments straight from
    // global (L2-resident 32 KB, shared by all blocks; MFMA ~1% of time) ----
    const int wave = t >> 6;           // 0..3 -> 32-col slab
    const int lane = t & 63;
    const int q    = lane >> 4;
    const int m    = lane & 15;
    const int wc   = wave * 32;

    f32x4 acc[2][2] = {};
    #pragma unroll
    for (int kb = 0; kb < 4; ++kb) {
        int ak = kb * 32 + q * 8;
        short8 af[2];
        #pragma unroll
        for (int rg = 0; rg < 2; ++rg)
            af[rg] = *(const short8*)&As[(rg * 16 + m) * 140 + ak];
        #pragma unroll
        for (int ct = 0; ct < 2; ++ct) {
            short8 bf = *(const short8*)(Wtb + (wc + ct * 16 + m) * D + ak);
            #pragma unroll
            for (int rg = 0; rg < 2; ++rg)
                acc[rg][ct] = __builtin_amdgcn_mfma_f32_16x16x32_bf16(
                    af[rg], bf, acc[rg][ct], 0, 0, 0);
        }
    }

    #pragma unroll
    for (int ct = 0; ct < 2; ++ct) {
        int col = wc + ct * 16 + m;
        float bc = bias[col];
        #pragma unroll
        for (int rg = 0; rg < 2; ++rg) {
            #pragma unroll
            for (int r = 0; r < 4; ++r) {
                int grow = row0 + rg * 16 + q * 4 + r;
                if (grow < NN) {
                    float v = acc[rg][ct][r] + bc;
                    if (relu) v = fmaxf(0.f, v);
                    if (outb) outb[(size_t)grow * D + col] = f2bf(v);
                    else __builtin_nontemporal_store(v, outf + (size_t)grow * D + col);
                }
            }
        }
    }
}

extern "C" void kernel_launch(void* const* d_in, const int* in_sizes, int n_in,
                              void* d_out, int out_size, void* d_ws, size_t ws_size,
                              hipStream_t stream)
{
    const float* x   = (const float*)d_in[0];
    const int*   ei  = (const int*)  d_in[1];
    const float* ew  = (const float*)d_in[2];
    const float* We1 = (const float*)d_in[3];
    const float* be1 = (const float*)d_in[4];
    const float* W1  = (const float*)d_in[5];
    const float* b1  = (const float*)d_in[6];
    const float* We2 = (const float*)d_in[7];
    const float* be2 = (const float*)d_in[8];
    const float* W2  = (const float*)d_in[9];
    const float* b2  = (const float*)d_in[10];

    float* out = (float*)d_out;

    // workspace (~33 MB)
    ushort* xb   = (ushort*)d_ws;                    // NN*D bf16
    ushort* hb   = xb + (size_t)NN * D;              // NN*D
    ushort* Wt1  = hb + (size_t)NN * D;              // 16384
    ushort* Wt2  = Wt1 + D * D;                      // 16384
    u64*   stage = (u64*)(Wt2 + D * D);              // NE u64
    int*   G     = (int*)(stage + NE);               // NC*NB (800 KB)
    int*   B     = G + NC * NB;                      // NB+1

    const int* src = ei;
    const int* dst = ei + NE;

    // ---- hist (LDS atomics, 32-node buckets) + W transpose ----
    hist_w<<<NC + 8, 256, 0, stream>>>(W1, W2, Wt1, Wt2, dst, G);

    // ---- bucket-grouped scatter (pair scan) + x cast ----
    scatter_cast<<<NC, 1024, 0, stream>>>(src, dst, ew, G, B, stage, x, xb);

    // ---- layer 1 (fused sort + aggregate + gemm) ----
    gine_layer<<<NB, 256, 0, stream>>>(xb, B, stage, We1, be1, Wt1, b1,
                                       nullptr, hb, 1);

    // ---- layer 2 (fused sort + aggregate + gemm) ----
    gine_layer<<<NB, 256, 0, stream>>>(hb, B, stage, We2, be2, Wt2, b2,
                                       out, nullptr, 0);
}